// Round 4
// baseline (159.563 us; speedup 1.0000x reference)
//
#include <hip/hip_runtime.h>
#include <hip/hip_bf16.h>
#include <math.h>

typedef __bf16 bf16_8 __attribute__((ext_vector_type(8)));
typedef float f32x4 __attribute__((ext_vector_type(4)));

#define D_ 256
#define S_ 128
#define E_ 512
#define MPE_ 4096
#define B_ 2
#define N_ 4096
#define M_TOT (B_*N_)   // 8192

__device__ __forceinline__ ushort f2b(float f) {
  union { float f; uint u; } x; x.f = f;
  uint r = (x.u + 0x7FFFu + ((x.u >> 16) & 1u)) >> 16;
  return (ushort)r;
}
__device__ __forceinline__ float b2f(ushort b) {
  union { uint u; float f; } x; x.u = ((uint)b) << 16;
  return x.f;
}

__device__ __forceinline__ void gl_lds16(const void* g, void* l) {
  __builtin_amdgcn_global_load_lds(
      (const __attribute__((address_space(1))) void*)g,
      (__attribute__((address_space(3))) void*)l, 16, 0, 0);
}

// ---------------- LayerNorm: one wave per row ----------------
__global__ __launch_bounds__(256) void ln_kernel(const float* __restrict__ q,
    const float* __restrict__ w, const float* __restrict__ b,
    ushort* __restrict__ x) {
  int wid = threadIdx.x >> 6, lane = threadIdx.x & 63;
  int row = blockIdx.x * 4 + wid;
  const float* qr = q + (size_t)row * D_;
  float4 v = *(const float4*)(qr + lane * 4);
  float s  = v.x + v.y + v.z + v.w;
  float ss = v.x*v.x + v.y*v.y + v.z*v.z + v.w*v.w;
  #pragma unroll
  for (int off = 32; off; off >>= 1) {
    s  += __shfl_xor(s, off);
    ss += __shfl_xor(ss, off);
  }
  float mu   = s * (1.0f / 256.0f);
  float var  = ss * (1.0f / 256.0f) - mu * mu;
  float rstd = rsqrtf(var + 1e-5f);
  ushort4 o;
  float vv[4] = {v.x, v.y, v.z, v.w};
  ushort ot[4];
  #pragma unroll
  for (int j = 0; j < 4; ++j) {
    int c = lane * 4 + j;
    ot[j] = f2b((vv[j] - mu) * rstd * w[c] + b[c]);
  }
  o.x = ot[0]; o.y = ot[1]; o.z = ot[2]; o.w = ot[3];
  *(ushort4*)(x + (size_t)row * D_ + lane * 4) = o;
}

// ---------------- weight transpose + cast ----------------
__global__ void wt_kernel(const float* __restrict__ in, ushort* __restrict__ out,
                          int R, int C) {
  int o = blockIdx.x * 256 + threadIdx.x;
  if (o >= R * C) return;
  int c = o / R, r = o - c * R;
  out[o] = f2b(in[r * C + c]);
}

// ---------------- GEMM: A[M][K] bf16, Bt[N][K] bf16, tile 128x64, BK=64 ----------------
template<int EPI>
__global__ __launch_bounds__(256) void gemm_kernel(
    const ushort* __restrict__ A, const ushort* __restrict__ Bt,
    const float* __restrict__ bias, void* __restrict__ out,
    int M, int N, int K) {
  __shared__ alignas(16) ushort As[128 * 64];
  __shared__ alignas(16) ushort Bs[64 * 64];
  int tid = threadIdx.x;
  int lane = tid & 63, wid = tid >> 6;
  int m0 = blockIdx.x * 128, n0 = blockIdx.y * 64;
  int r16 = lane & 15, kq = lane >> 4;
  f32x4 acc[2][4] = {};
  for (int k0 = 0; k0 < K; k0 += 64) {
    __syncthreads();
    #pragma unroll
    for (int t = 0; t < 4; ++t) {
      int cid = tid + t * 256;
      int row = cid >> 3, c = cid & 7;
      uint4 d = *(const uint4*)(A + ((size_t)(m0 + row) * K + k0 + c * 8));
      *(uint4*)&As[row * 64 + ((c ^ (row & 7)) * 8)] = d;
    }
    #pragma unroll
    for (int t = 0; t < 2; ++t) {
      int cid = tid + t * 256;
      int row = cid >> 3, c = cid & 7;
      uint4 d = *(const uint4*)(Bt + ((size_t)(n0 + row) * K + k0 + c * 8));
      *(uint4*)&Bs[row * 64 + ((c ^ (row & 7)) * 8)] = d;
    }
    __syncthreads();
    #pragma unroll
    for (int ks = 0; ks < 2; ++ks) {
      bf16_8 af[2], bfr[4];
      int c = ks * 4 + kq;
      #pragma unroll
      for (int fm = 0; fm < 2; ++fm) {
        int r = wid * 32 + fm * 16 + r16;
        af[fm] = *(const bf16_8*)&As[r * 64 + ((c ^ (r & 7)) * 8)];
      }
      #pragma unroll
      for (int fn = 0; fn < 4; ++fn) {
        int r = fn * 16 + r16;
        bfr[fn] = *(const bf16_8*)&Bs[r * 64 + ((c ^ (r & 7)) * 8)];
      }
      #pragma unroll
      for (int fm = 0; fm < 2; ++fm)
        #pragma unroll
        for (int fn = 0; fn < 4; ++fn)
          acc[fm][fn] = __builtin_amdgcn_mfma_f32_16x16x32_bf16(af[fm], bfr[fn], acc[fm][fn], 0, 0, 0);
    }
  }
  #pragma unroll
  for (int fm = 0; fm < 2; ++fm)
    #pragma unroll
    for (int fn = 0; fn < 4; ++fn)
      #pragma unroll
      for (int reg = 0; reg < 4; ++reg) {
        int ml = wid * 32 + fm * 16 + kq * 4 + reg;
        int nl = fn * 16 + r16;
        size_t gm = m0 + ml, gn = n0 + nl;
        float val = acc[fm][fn][reg] + bias[gn];
        if (EPI == 0) {
          float y = val / (1.0f + expf(-val));
          ((ushort*)out)[gm * N + gn] = f2b(y);
        } else if (EPI == 2) {
          float y = val / (1.0f + expf(-val));
          ((ushort*)out)[gn * (size_t)M_TOT + gm] = f2b(y);
        } else {
          ((float*)out)[gm * N + gn] = val;
        }
      }
}

// ---------------- RoPE (outputs pre-scaled by 1/64 so q.k carries 1/MPE) ----------------
__global__ __launch_bounds__(256) void rope_kernel(const ushort* __restrict__ base,
    const float* __restrict__ qw, const float* __restrict__ qb,
    const float* __restrict__ kw, const float* __restrict__ kb,
    ushort* __restrict__ Q, ushort* __restrict__ Kk) {
  int g = blockIdx.x * 256 + threadIdx.x;
  int row = g >> 6, i = g & 63;
  int n = row & (N_ - 1);
  float invf = powf(10000.0f, -(float)i * (1.0f / 64.0f));
  float sv, cv;
  sincosf((float)n * invf, &sv, &cv);
  const float sc = 0.015625f;   // 1/64; (1/64)^2 = 1/4096 = 1/MPE
  float b1 = b2f(base[row * S_ + i]), b2 = b2f(base[row * S_ + 64 + i]);
  float x1q = b1 * qw[i] + qb[i], x2q = b2 * qw[64 + i] + qb[64 + i];
  Q[row * S_ + i]      = f2b((x1q * cv - x2q * sv) * sc);
  Q[row * S_ + 64 + i] = f2b((x2q * cv + x1q * sv) * sc);
  float x1k = b1 * kw[i] + kb[i], x2k = b2 * kw[64 + i] + kb[64 + i];
  Kk[row * S_ + i]      = f2b((x1k * cv - x2k * sv) * sc);
  Kk[row * S_ + 64 + i] = f2b((x2k * cv + x1k * sv) * sc);
}

// ---------------- fused attention ----------------
// grid (64 m-tiles of 64, 4 e-chunks of 128, 2 b) = 512 blocks, 4 waves.
// Swapped QK: sacc = mfma(K_frag, Q_frag) -> lane holds 4 consecutive n at
// fixed m => packed b64 P-writes (cvt_pk) + b128 bias gathers (4 rotated
// copies of the w_rel window make them 16B-aligned).
__global__ __launch_bounds__(256, 2) void attn_kernel(
    const ushort* __restrict__ Q, const ushort* __restrict__ Kd,
    const ushort* __restrict__ VT, const ushort* __restrict__ U,
    const float* __restrict__ w_rel, ushort* __restrict__ KVU) {
  __shared__ alignas(16) ushort Ks[2][64 * 128];   // 32 KB
  __shared__ alignas(16) ushort Vs[2][128 * 64];   // 32 KB
  __shared__ alignas(16) ushort Pb[2][32 * 64];    // 8 KB (per m-group)
  __shared__ alignas(16) float WrLc[2][4][132];    // 4.2 KB (4 rotated copies)
  const int tid = threadIdx.x, lane = tid & 63, wid = tid >> 6;
  const int b = blockIdx.z, m0 = blockIdx.x * 64, e0 = blockIdx.y * 128;
  const int r16 = lane & 15, kq = lane >> 4;
  const int wm = wid >> 1, wl = wid & 1;
  const int jw = tid & 127, cpair = tid >> 7;     // w_rel window staging

  // Q fragments: wave's 32 m-rows x 128 k (used as B-operand: col=m, k=s)
  bf16_8 qf[2][4];
  #pragma unroll
  for (int fm = 0; fm < 2; ++fm)
    #pragma unroll
    for (int ks = 0; ks < 4; ++ks)
      qf[fm][ks] = *(const bf16_8*)(Q +
          ((size_t)(b * N_ + m0 + wm * 32 + fm * 16 + r16) * S_ + ks * 32 + kq * 8));

  auto stage_kv = [&](int bi, int t) {
    int n0s = t * 64;
    #pragma unroll
    for (int tt = 0; tt < 4; ++tt) {           // K tile: 64 rows x 16 chunks
      int p = tt * 256 + wid * 64 + lane;
      int row = p >> 4, sc2 = p & 15;
      int cc = sc2 ^ (row & 7);
      gl_lds16(Kd + ((size_t)(b * N_ + n0s + row) * S_ + cc * 8),
               &Ks[bi][(tt * 256 + wid * 64) * 8]);
    }
    #pragma unroll
    for (int tt = 0; tt < 4; ++tt) {           // V^T tile: 128 e-rows x 8 chunks
      int p = tt * 256 + wid * 64 + lane;
      int er = p >> 3, sc2 = p & 7;
      int nc = sc2 ^ (er & 7);
      gl_lds16(VT + ((size_t)(e0 + er) * M_TOT + b * N_ + n0s + nc * 8),
               &Vs[bi][(tt * 256 + wid * 64) * 8]);
    }
  };

  auto wr_load = [&](int t) -> float {
    int idx = 4032 + t * 64 - m0 + jw;
    if (idx > 8190) idx = 8190;
    return w_rel[idx];
  };
  auto wr_store = [&](int bi, float v) {
    WrLc[bi][cpair][jw + cpair] = v;
    WrLc[bi][cpair + 2][jw + cpair + 2] = v;
  };

  f32x4 pv[2][4] = {};

  stage_kv(0, 0);
  wr_store(0, wr_load(0));
  asm volatile("s_waitcnt vmcnt(0) lgkmcnt(0)" ::: "memory");
  __builtin_amdgcn_s_barrier();

  // per-lane bias-gather constants: copy c, base offset
  const int csel = (r16 + 1) & 3;
  const int abase = 63 + (wl - wm) * 32 + 4 * kq - r16 + csel;

  auto body = [&](int CUR, int t) {
    float wv = 0.f;
    if (t < 63) wv = wr_load(t + 1);
    if (t < 63) stage_kv(CUR ^ 1, t + 1);
    const ushort* ksb = Ks[CUR];
    // ---- QK (swapped): sacc[fm][fn] = K_frag x Q_frag -> col=m, row=n ----
    f32x4 sacc[2][2] = {};
    __builtin_amdgcn_s_setprio(1);
    #pragma unroll
    for (int ks = 0; ks < 4; ++ks) {
      bf16_8 kf[2];
      #pragma unroll
      for (int fn = 0; fn < 2; ++fn) {
        int r = wl * 32 + fn * 16 + r16;
        int c = ks * 4 + kq;
        kf[fn] = *(const bf16_8*)&ksb[r * 128 + ((c ^ (r & 7)) * 8)];
      }
      #pragma unroll
      for (int fm = 0; fm < 2; ++fm)
        #pragma unroll
        for (int fn = 0; fn < 2; ++fn)
          sacc[fm][fn] = __builtin_amdgcn_mfma_f32_16x16x32_bf16(kf[fn], qf[fm][ks], sacc[fm][fn], 0, 0, 0);
    }
    __builtin_amdgcn_s_setprio(0);
    if (t < 63) wr_store(CUR ^ 1, wv);
    // ---- transform -> Pb[wm]: packed b64 writes, b128 bias gathers ----
    char* psb = (char*)&Pb[wm][0];
    #pragma unroll
    for (int fm = 0; fm < 2; ++fm)
      #pragma unroll
      for (int fn = 0; fn < 2; ++fn) {
        int a = abase + fn * 16 - fm * 16;
        float4 b4 = *(const float4*)&WrLc[CUR][csel][a];
        float t0 = fmaxf(sacc[fm][fn][0] + b4.x, 0.f);
        float t1 = fmaxf(sacc[fm][fn][1] + b4.y, 0.f);
        float t2 = fmaxf(sacc[fm][fn][2] + b4.z, 0.f);
        float t3 = fmaxf(sacc[fm][fn][3] + b4.w, 0.f);
        t0 *= t0; t1 *= t1; t2 *= t2; t3 *= t3;
        uint p01, p23;
        asm("v_cvt_pk_bf16_f32 %0, %1, %2" : "=v"(p01) : "v"(t0), "v"(t1));
        asm("v_cvt_pk_bf16_f32 %0, %1, %2" : "=v"(p23) : "v"(t2), "v"(t3));
        int mp = fm * 16 + r16;
        int nb2 = wl * 64 + fn * 32 + kq * 8;   // byte offset of n within row
        uint2 pk; pk.x = p01; pk.y = p23;
        *(uint2*)(psb + ((mp * 128 + nb2) ^ ((mp & 7) << 4))) = pk;
      }
    asm volatile("s_waitcnt lgkmcnt(0)" ::: "memory");
    __builtin_amdgcn_s_barrier();
    // ---- PV: out[32m x 64e] per wave (waves 2m x 2e), k = 64n ----
    const ushort* vsb = Vs[CUR];
    __builtin_amdgcn_s_setprio(1);
    #pragma unroll
    for (int ks = 0; ks < 2; ++ks) {
      bf16_8 pa[2];
      #pragma unroll
      for (int fm = 0; fm < 2; ++fm) {
        int r = fm * 16 + r16;
        pa[fm] = *(const bf16_8*)(psb + ((r * 128 + ks * 64 + kq * 16) ^ ((r & 7) << 4)));
      }
      #pragma unroll
      for (int fe = 0; fe < 4; ++fe) {
        int rv = wl * 64 + fe * 16 + r16;
        int cv = ks * 4 + kq;
        bf16_8 vf = *(const bf16_8*)&vsb[rv * 64 + ((cv ^ (rv & 7)) * 8)];
        #pragma unroll
        for (int fm = 0; fm < 2; ++fm)
          pv[fm][fe] = __builtin_amdgcn_mfma_f32_16x16x32_bf16(pa[fm], vf, pv[fm][fe], 0, 0, 0);
      }
    }
    __builtin_amdgcn_s_setprio(0);
    asm volatile("s_waitcnt vmcnt(0) lgkmcnt(0)" ::: "memory");
    __builtin_amdgcn_s_barrier();
  };

  for (int t2 = 0; t2 < 32; ++t2) {
    body(0, 2 * t2);
    body(1, 2 * t2 + 1);
  }

  // ---- epilogue: KVU = bf16(u * pv) ----
  #pragma unroll
  for (int fm = 0; fm < 2; ++fm)
    #pragma unroll
    for (int fe = 0; fe < 4; ++fe)
      #pragma unroll
      for (int reg = 0; reg < 4; ++reg) {
        int ml = fm * 16 + kq * 4 + reg;
        size_t grow = (size_t)b * N_ + m0 + wm * 32 + ml;
        size_t ge = e0 + wl * 64 + fe * 16 + r16;
        float uu = b2f(U[grow * E_ + ge]);
        KVU[grow * E_ + ge] = f2b(uu * pv[fm][fe][reg]);
      }
}

extern "C" void kernel_launch(void* const* d_in, const int* in_sizes, int n_in,
                              void* d_out, int out_size, void* d_ws, size_t ws_size,
                              hipStream_t stream) {
  const float* query = (const float*)d_in[0];
  const float* ln_w  = (const float*)d_in[1];
  const float* ln_b  = (const float*)d_in[2];
  const float* Wu    = (const float*)d_in[3];
  const float* bu    = (const float*)d_in[4];
  const float* Wv    = (const float*)d_in[5];
  const float* bv    = (const float*)d_in[6];
  const float* Wbase = (const float*)d_in[7];
  const float* bbase = (const float*)d_in[8];
  const float* q_w   = (const float*)d_in[9];
  const float* q_b   = (const float*)d_in[10];
  const float* k_w   = (const float*)d_in[11];
  const float* k_b   = (const float*)d_in[12];
  const float* w_rel = (const float*)d_in[13];
  const float* Wo    = (const float*)d_in[14];
  const float* bo    = (const float*)d_in[15];
  float* out = (float*)d_out;

  char* ws = (char*)d_ws;
  ushort* X    = (ushort*)(ws);                     // 8192*256  (4 MB)
  ushort* U    = (ushort*)(ws + (4u  << 20));       // 8192*512  (8 MB)
  ushort* VT   = (ushort*)(ws + (12u << 20));       // 512*8192  (8 MB)
  ushort* BASE = (ushort*)(ws + (20u << 20));       // 8192*128  (2 MB)
  ushort* Qb   = (ushort*)(ws + (22u << 20));       // 2 MB
  ushort* Kb   = (ushort*)(ws + (24u << 20));       // 2 MB
  ushort* KVU  = (ushort*)(ws + (26u << 20));       // 8 MB
  ushort* WUT  = (ushort*)(ws + (34u << 20));
  ushort* WVT  = (ushort*)(ws + (34u << 20) + 512*256*2);
  ushort* WBT  = (ushort*)(ws + (34u << 20) + 2*512*256*2);
  ushort* WOT  = (ushort*)(ws + (34u << 20) + 2*512*256*2 + 128*256*2);

  ln_kernel<<<2048, 256, 0, stream>>>(query, ln_w, ln_b, X);
  wt_kernel<<<(512*256 + 255) / 256, 256, 0, stream>>>(Wu, WUT, 256, 512);
  wt_kernel<<<(512*256 + 255) / 256, 256, 0, stream>>>(Wv, WVT, 256, 512);
  wt_kernel<<<(128*256 + 255) / 256, 256, 0, stream>>>(Wbase, WBT, 256, 128);
  wt_kernel<<<(512*256 + 255) / 256, 256, 0, stream>>>(Wo, WOT, 512, 256);
  gemm_kernel<0><<<dim3(64, 8), 256, 0, stream>>>(X, WUT, bu, U, 8192, 512, 256);
  gemm_kernel<2><<<dim3(64, 8), 256, 0, stream>>>(X, WVT, bv, VT, 8192, 512, 256);
  gemm_kernel<0><<<dim3(64, 2), 256, 0, stream>>>(X, WBT, bbase, BASE, 8192, 128, 256);
  rope_kernel<<<2048, 256, 0, stream>>>(BASE, q_w, q_b, k_w, k_b, Qb, Kb);
  attn_kernel<<<dim3(64, 4, 2), 256, 0, stream>>>(Qb, Kb, VT, U, w_rel, KVU);
  gemm_kernel<1><<<dim3(64, 4), 256, 0, stream>>>(KVU, WOT, bo, out, 8192, 256, 512);
}

// Round 5
// 159.300 us; speedup vs baseline: 1.0017x; 1.0017x over previous
//
#include <hip/hip_runtime.h>
#include <hip/hip_bf16.h>
#include <math.h>

typedef __bf16 bf16_8 __attribute__((ext_vector_type(8)));
typedef float f32x4 __attribute__((ext_vector_type(4)));

#define D_ 256
#define S_ 128
#define E_ 512
#define MPE_ 4096
#define B_ 2
#define N_ 4096
#define M_TOT (B_*N_)   // 8192

__device__ __forceinline__ ushort f2b(float f) {
  union { float f; uint u; } x; x.f = f;
  uint r = (x.u + 0x7FFFu + ((x.u >> 16) & 1u)) >> 16;
  return (ushort)r;
}
__device__ __forceinline__ float b2f(ushort b) {
  union { uint u; float f; } x; x.u = ((uint)b) << 16;
  return x.f;
}

__device__ __forceinline__ void gl_lds16(const void* g, void* l) {
  __builtin_amdgcn_global_load_lds(
      (const __attribute__((address_space(1))) void*)g,
      (__attribute__((address_space(3))) void*)l, 16, 0, 0);
}

// ---------------- LayerNorm: one wave per row ----------------
__global__ __launch_bounds__(256) void ln_kernel(const float* __restrict__ q,
    const float* __restrict__ w, const float* __restrict__ b,
    ushort* __restrict__ x) {
  int wid = threadIdx.x >> 6, lane = threadIdx.x & 63;
  int row = blockIdx.x * 4 + wid;
  const float* qr = q + (size_t)row * D_;
  float4 v = *(const float4*)(qr + lane * 4);
  float s  = v.x + v.y + v.z + v.w;
  float ss = v.x*v.x + v.y*v.y + v.z*v.z + v.w*v.w;
  #pragma unroll
  for (int off = 32; off; off >>= 1) {
    s  += __shfl_xor(s, off);
    ss += __shfl_xor(ss, off);
  }
  float mu   = s * (1.0f / 256.0f);
  float var  = ss * (1.0f / 256.0f) - mu * mu;
  float rstd = rsqrtf(var + 1e-5f);
  ushort4 o;
  float vv[4] = {v.x, v.y, v.z, v.w};
  ushort ot[4];
  #pragma unroll
  for (int j = 0; j < 4; ++j) {
    int c = lane * 4 + j;
    ot[j] = f2b((vv[j] - mu) * rstd * w[c] + b[c]);
  }
  o.x = ot[0]; o.y = ot[1]; o.z = ot[2]; o.w = ot[3];
  *(ushort4*)(x + (size_t)row * D_ + lane * 4) = o;
}

// ---------------- weight transpose + cast ----------------
__global__ void wt_kernel(const float* __restrict__ in, ushort* __restrict__ out,
                          int R, int C) {
  int o = blockIdx.x * 256 + threadIdx.x;
  if (o >= R * C) return;
  int c = o / R, r = o - c * R;
  out[o] = f2b(in[r * C + c]);
}

// ---------------- GEMM: A[M][K] bf16, Bt[N][K] bf16, tile 128x64, BK=64 ----------------
template<int EPI>
__global__ __launch_bounds__(256) void gemm_kernel(
    const ushort* __restrict__ A, const ushort* __restrict__ Bt,
    const float* __restrict__ bias, void* __restrict__ out,
    int M, int N, int K) {
  __shared__ alignas(16) ushort As[128 * 64];
  __shared__ alignas(16) ushort Bs[64 * 64];
  int tid = threadIdx.x;
  int lane = tid & 63, wid = tid >> 6;
  int m0 = blockIdx.x * 128, n0 = blockIdx.y * 64;
  int r16 = lane & 15, kq = lane >> 4;
  f32x4 acc[2][4] = {};
  for (int k0 = 0; k0 < K; k0 += 64) {
    __syncthreads();
    #pragma unroll
    for (int t = 0; t < 4; ++t) {
      int cid = tid + t * 256;
      int row = cid >> 3, c = cid & 7;
      uint4 d = *(const uint4*)(A + ((size_t)(m0 + row) * K + k0 + c * 8));
      *(uint4*)&As[row * 64 + ((c ^ (row & 7)) * 8)] = d;
    }
    #pragma unroll
    for (int t = 0; t < 2; ++t) {
      int cid = tid + t * 256;
      int row = cid >> 3, c = cid & 7;
      uint4 d = *(const uint4*)(Bt + ((size_t)(n0 + row) * K + k0 + c * 8));
      *(uint4*)&Bs[row * 64 + ((c ^ (row & 7)) * 8)] = d;
    }
    __syncthreads();
    #pragma unroll
    for (int ks = 0; ks < 2; ++ks) {
      bf16_8 af[2], bfr[4];
      int c = ks * 4 + kq;
      #pragma unroll
      for (int fm = 0; fm < 2; ++fm) {
        int r = wid * 32 + fm * 16 + r16;
        af[fm] = *(const bf16_8*)&As[r * 64 + ((c ^ (r & 7)) * 8)];
      }
      #pragma unroll
      for (int fn = 0; fn < 4; ++fn) {
        int r = fn * 16 + r16;
        bfr[fn] = *(const bf16_8*)&Bs[r * 64 + ((c ^ (r & 7)) * 8)];
      }
      #pragma unroll
      for (int fm = 0; fm < 2; ++fm)
        #pragma unroll
        for (int fn = 0; fn < 4; ++fn)
          acc[fm][fn] = __builtin_amdgcn_mfma_f32_16x16x32_bf16(af[fm], bfr[fn], acc[fm][fn], 0, 0, 0);
    }
  }
  #pragma unroll
  for (int fm = 0; fm < 2; ++fm)
    #pragma unroll
    for (int fn = 0; fn < 4; ++fn)
      #pragma unroll
      for (int reg = 0; reg < 4; ++reg) {
        int ml = wid * 32 + fm * 16 + kq * 4 + reg;
        int nl = fn * 16 + r16;
        size_t gm = m0 + ml, gn = n0 + nl;
        float val = acc[fm][fn][reg] + bias[gn];
        if (EPI == 0) {
          float y = val / (1.0f + expf(-val));
          ((ushort*)out)[gm * N + gn] = f2b(y);
        } else if (EPI == 2) {
          float y = val / (1.0f + expf(-val));
          ((ushort*)out)[gn * (size_t)M_TOT + gm] = f2b(y);
        } else {
          ((float*)out)[gm * N + gn] = val;
        }
      }
}

// ---------------- RoPE (outputs pre-scaled by 1/64 so q.k carries 1/MPE) ----------------
__global__ __launch_bounds__(256) void rope_kernel(const ushort* __restrict__ base,
    const float* __restrict__ qw, const float* __restrict__ qb,
    const float* __restrict__ kw, const float* __restrict__ kb,
    ushort* __restrict__ Q, ushort* __restrict__ Kk) {
  int g = blockIdx.x * 256 + threadIdx.x;
  int row = g >> 6, i = g & 63;
  int n = row & (N_ - 1);
  float invf = powf(10000.0f, -(float)i * (1.0f / 64.0f));
  float sv, cv;
  sincosf((float)n * invf, &sv, &cv);
  const float sc = 0.015625f;   // 1/64; (1/64)^2 = 1/4096 = 1/MPE
  float b1 = b2f(base[row * S_ + i]), b2 = b2f(base[row * S_ + 64 + i]);
  float x1q = b1 * qw[i] + qb[i], x2q = b2 * qw[64 + i] + qb[64 + i];
  Q[row * S_ + i]      = f2b((x1q * cv - x2q * sv) * sc);
  Q[row * S_ + 64 + i] = f2b((x2q * cv + x1q * sv) * sc);
  float x1k = b1 * kw[i] + kb[i], x2k = b2 * kw[64 + i] + kb[64 + i];
  Kk[row * S_ + i]      = f2b((x1k * cv - x2k * sv) * sc);
  Kk[row * S_ + 64 + i] = f2b((x2k * cv + x1k * sv) * sc);
}

// ---------------- fused attention ----------------
// grid (32 m-tiles of 128, 4 e-chunks of 128, 2 b) = 256 blocks, 512 thr (8 waves),
// 1 block/CU (86.4KB LDS), 2 waves/SIMD. Q in regs (64 VGPR). K/V double-buffered
// via global_load_lds (pre-swizzled source). QK waves 2m x 4n (kf reused 4x);
// PV waves 4m x 2e. Bias: 4 shifted copies at stride 200 (=8 mod 32, =0 mod 4)
// with csel=r16&3 -> aligned float4 reads, exactly-2-way banks (free).
__global__ __launch_bounds__(512, 2) void attn_kernel(
    const ushort* __restrict__ Q, const ushort* __restrict__ Kd,
    const ushort* __restrict__ VT, const ushort* __restrict__ U,
    const float* __restrict__ w_rel, ushort* __restrict__ KVU) {
  __shared__ alignas(16) ushort Ks[2][64 * 128];   // 32 KB
  __shared__ alignas(16) ushort Vs[2][128 * 64];   // 32 KB
  __shared__ alignas(16) ushort Pb[128 * 64];      // 16 KB
  __shared__ alignas(16) float WrLc[2][4][200];    // 6.4 KB
  const int tid = threadIdx.x, lane = tid & 63, wid = tid >> 6;
  const int b = blockIdx.z, m0 = blockIdx.x * 128, e0 = blockIdx.y * 128;
  const int r16 = lane & 15, kq = lane >> 4;
  const int wqm = wid >> 2, wqn = wid & 3;   // QK: 2m x 4n
  const int wpm = wid >> 1, wpe = wid & 1;   // PV: 4m x 2e

  // Q fragments: wave's 64 m-rows x 128 k (B-operand: col=m)
  bf16_8 qf[4][4];
  #pragma unroll
  for (int fm = 0; fm < 4; ++fm)
    #pragma unroll
    for (int ks = 0; ks < 4; ++ks)
      qf[fm][ks] = *(const bf16_8*)(Q +
          ((size_t)(b * N_ + m0 + wqm * 64 + fm * 16 + r16) * S_ + ks * 32 + kq * 8));

  auto stage_kv = [&](int bi, int t) {
    int n0s = t * 64;
    #pragma unroll
    for (int tt = 0; tt < 2; ++tt) {           // K tile: 64n x 128s = 1024 chunks
      int p = tt * 512 + tid;
      int row = p >> 4, sc2 = p & 15;
      int cc = sc2 ^ (row & 7);
      gl_lds16(Kd + ((size_t)(b * N_ + n0s + row) * S_ + cc * 8),
               &Ks[bi][(tt * 512 + wid * 64) * 8]);
    }
    #pragma unroll
    for (int tt = 0; tt < 2; ++tt) {           // V^T tile: 128e x 64n = 1024 chunks
      int p = tt * 512 + tid;
      int er = p >> 3, sc2 = p & 7;
      int nc = sc2 ^ (er & 7);
      gl_lds16(VT + ((size_t)(e0 + er) * M_TOT + b * N_ + n0s + nc * 8),
               &Vs[bi][(tt * 512 + wid * 64) * 8]);
    }
  };

  // bias window staging: copy c at x holds w_rel[W0 + x - 1 - c], 4 copies x 200
  const int bi0 = tid, bi1 = tid + 512;
  const int bc0 = bi0 / 200, bx0 = bi0 - bc0 * 200;
  const int bc1 = bi1 / 200, bx1 = bi1 - bc1 * 200;
  const bool bp1 = bi1 < 800;
  auto wr_load = [&](int t, float& w0, float& w1) {
    int W0 = 3968 + t * 64 - m0;
    int i0 = W0 + bx0 - 1 - bc0;
    i0 = i0 < 0 ? 0 : (i0 > 8190 ? 8190 : i0);
    w0 = w_rel[i0];
    int i1 = W0 + bx1 - 1 - bc1;
    i1 = i1 < 0 ? 0 : (i1 > 8190 ? 8190 : i1);
    w1 = bp1 ? w_rel[i1] : 0.f;
  };
  auto wr_store = [&](int bi, float w0, float w1) {
    WrLc[bi][bc0][bx0] = w0;
    if (bp1) WrLc[bi][bc1][bx1] = w1;
  };

  f32x4 pv[2][4] = {};

  {
    float w0, w1;
    wr_load(0, w0, w1);
    stage_kv(0, 0);
    wr_store(0, w0, w1);
  }
  asm volatile("s_waitcnt vmcnt(0) lgkmcnt(0)" ::: "memory");
  __builtin_amdgcn_s_barrier();

  // bias read constants: a = 128 + 4kq + 16wqn - 64wqm - r16 + csel - 16fm
  const int csel = r16 & 3;
  const int abase = 128 + 4 * kq + 16 * wqn - 64 * wqm - r16 + csel;

  auto body = [&](int CUR, int t) {
    float w0 = 0.f, w1 = 0.f;
    if (t < 63) wr_load(t + 1, w0, w1);
    if (t < 63) stage_kv(CUR ^ 1, t + 1);
    const ushort* ksb = Ks[CUR];
    // ---- QK (swapped): sacc[fm] = K_frag x Q_frag -> col=m, rows=n ----
    f32x4 sacc[4] = {};
    __builtin_amdgcn_s_setprio(1);
    #pragma unroll
    for (int ks = 0; ks < 4; ++ks) {
      int r = wqn * 16 + r16;
      int c = ks * 4 + kq;
      bf16_8 kf = *(const bf16_8*)&ksb[r * 128 + ((c ^ (r & 7)) * 8)];
      #pragma unroll
      for (int fm = 0; fm < 4; ++fm)
        sacc[fm] = __builtin_amdgcn_mfma_f32_16x16x32_bf16(kf, qf[fm][ks], sacc[fm], 0, 0, 0);
    }
    __builtin_amdgcn_s_setprio(0);
    if (t < 63) wr_store(CUR ^ 1, w0, w1);
    // ---- transform -> Pb: aligned float4 bias reads + packed uint2 P writes ----
    char* psb = (char*)&Pb[0];
    #pragma unroll
    for (int fm = 0; fm < 4; ++fm) {
      float4 b4 = *(const float4*)&WrLc[CUR][csel][abase - fm * 16];
      float t0 = fmaxf(sacc[fm][0] + b4.x, 0.f);
      float t1 = fmaxf(sacc[fm][1] + b4.y, 0.f);
      float t2 = fmaxf(sacc[fm][2] + b4.z, 0.f);
      float t3 = fmaxf(sacc[fm][3] + b4.w, 0.f);
      t0 *= t0; t1 *= t1; t2 *= t2; t3 *= t3;
      uint p01, p23;
      asm("v_cvt_pk_bf16_f32 %0, %1, %2" : "=v"(p01) : "v"(t0), "v"(t1));
      asm("v_cvt_pk_bf16_f32 %0, %1, %2" : "=v"(p23) : "v"(t2), "v"(t3));
      int mp = wqm * 64 + fm * 16 + r16;
      int nb2 = wqn * 32 + kq * 8;
      uint2 pk; pk.x = p01; pk.y = p23;
      *(uint2*)(psb + ((mp * 128 + nb2) ^ ((mp & 7) << 4))) = pk;
    }
    asm volatile("s_waitcnt lgkmcnt(0)" ::: "memory");
    __builtin_amdgcn_s_barrier();
    // ---- PV: out[32m x 64e] per wave (waves 4m x 2e), k = 64n ----
    const ushort* vsb = Vs[CUR];
    __builtin_amdgcn_s_setprio(1);
    #pragma unroll
    for (int ks = 0; ks < 2; ++ks) {
      bf16_8 pa[2];
      #pragma unroll
      for (int fm = 0; fm < 2; ++fm) {
        int r = wpm * 32 + fm * 16 + r16;
        pa[fm] = *(const bf16_8*)(psb + ((r * 128 + ks * 64 + kq * 16) ^ ((r & 7) << 4)));
      }
      #pragma unroll
      for (int fe = 0; fe < 4; ++fe) {
        int rv = wpe * 64 + fe * 16 + r16;
        int cv = ks * 4 + kq;
        bf16_8 vf = *(const bf16_8*)&vsb[rv * 64 + ((cv ^ (rv & 7)) * 8)];
        #pragma unroll
        for (int fm = 0; fm < 2; ++fm)
          pv[fm][fe] = __builtin_amdgcn_mfma_f32_16x16x32_bf16(pa[fm], vf, pv[fm][fe], 0, 0, 0);
      }
    }
    __builtin_amdgcn_s_setprio(0);
    asm volatile("s_waitcnt vmcnt(0) lgkmcnt(0)" ::: "memory");
    __builtin_amdgcn_s_barrier();
  };

  for (int t2 = 0; t2 < 32; ++t2) {
    body(0, 2 * t2);
    body(1, 2 * t2 + 1);
  }

  // ---- epilogue: KVU = bf16(u * pv) ----
  #pragma unroll
  for (int fm = 0; fm < 2; ++fm)
    #pragma unroll
    for (int fe = 0; fe < 4; ++fe)
      #pragma unroll
      for (int reg = 0; reg < 4; ++reg) {
        int ml = wpm * 32 + fm * 16 + kq * 4 + reg;
        size_t grow = (size_t)b * N_ + m0 + ml;
        size_t ge = e0 + wpe * 64 + fe * 16 + r16;
        float uu = b2f(U[grow * E_ + ge]);
        KVU[grow * E_ + ge] = f2b(uu * pv[fm][fe][reg]);
      }
}

extern "C" void kernel_launch(void* const* d_in, const int* in_sizes, int n_in,
                              void* d_out, int out_size, void* d_ws, size_t ws_size,
                              hipStream_t stream) {
  const float* query = (const float*)d_in[0];
  const float* ln_w  = (const float*)d_in[1];
  const float* ln_b  = (const float*)d_in[2];
  const float* Wu    = (const float*)d_in[3];
  const float* bu    = (const float*)d_in[4];
  const float* Wv    = (const float*)d_in[5];
  const float* bv    = (const float*)d_in[6];
  const float* Wbase = (const float*)d_in[7];
  const float* bbase = (const float*)d_in[8];
  const float* q_w   = (const float*)d_in[9];
  const float* q_b   = (const float*)d_in[10];
  const float* k_w   = (const float*)d_in[11];
  const float* k_b   = (const float*)d_in[12];
  const float* w_rel = (const float*)d_in[13];
  const float* Wo    = (const float*)d_in[14];
  const float* bo    = (const float*)d_in[15];
  float* out = (float*)d_out;

  char* ws = (char*)d_ws;
  ushort* X    = (ushort*)(ws);                     // 8192*256  (4 MB)
  ushort* U    = (ushort*)(ws + (4u  << 20));       // 8192*512  (8 MB)
  ushort* VT   = (ushort*)(ws + (12u << 20));       // 512*8192  (8 MB)
  ushort* BASE = (ushort*)(ws + (20u << 20));       // 8192*128  (2 MB)
  ushort* Qb   = (ushort*)(ws + (22u << 20));       // 2 MB
  ushort* Kb   = (ushort*)(ws + (24u << 20));       // 2 MB
  ushort* KVU  = (ushort*)(ws + (26u << 20));       // 8 MB
  ushort* WUT  = (ushort*)(ws + (34u << 20));
  ushort* WVT  = (ushort*)(ws + (34u << 20) + 512*256*2);
  ushort* WBT  = (ushort*)(ws + (34u << 20) + 2*512*256*2);
  ushort* WOT  = (ushort*)(ws + (34u << 20) + 2*512*256*2 + 128*256*2);

  ln_kernel<<<2048, 256, 0, stream>>>(query, ln_w, ln_b, X);
  wt_kernel<<<(512*256 + 255) / 256, 256, 0, stream>>>(Wu, WUT, 256, 512);
  wt_kernel<<<(512*256 + 255) / 256, 256, 0, stream>>>(Wv, WVT, 256, 512);
  wt_kernel<<<(128*256 + 255) / 256, 256, 0, stream>>>(Wbase, WBT, 256, 128);
  wt_kernel<<<(512*256 + 255) / 256, 256, 0, stream>>>(Wo, WOT, 512, 256);
  gemm_kernel<0><<<dim3(64, 8), 256, 0, stream>>>(X, WUT, bu, U, 8192, 512, 256);
  gemm_kernel<2><<<dim3(64, 8), 256, 0, stream>>>(X, WVT, bv, VT, 8192, 512, 256);
  gemm_kernel<0><<<dim3(64, 2), 256, 0, stream>>>(X, WBT, bbase, BASE, 8192, 128, 256);
  rope_kernel<<<2048, 256, 0, stream>>>(BASE, q_w, q_b, k_w, k_b, Qb, Kb);
  attn_kernel<<<dim3(32, 4, 2), 512, 0, stream>>>(Qb, Kb, VT, U, w_rel, KVU);
  gemm_kernel<1><<<dim3(64, 4), 256, 0, stream>>>(KVU, WOT, bo, out, 8192, 256, 512);
}

// Round 6
// 146.051 us; speedup vs baseline: 1.0925x; 1.0907x over previous
//
#include <hip/hip_runtime.h>
#include <hip/hip_bf16.h>
#include <math.h>

typedef __bf16 bf16_8 __attribute__((ext_vector_type(8)));
typedef float f32x4 __attribute__((ext_vector_type(4)));

#define D_ 256
#define S_ 128
#define E_ 512
#define MPE_ 4096
#define B_ 2
#define N_ 4096
#define M_TOT (B_*N_)   // 8192

__device__ __forceinline__ ushort f2b(float f) {
  union { float f; uint u; } x; x.f = f;
  uint r = (x.u + 0x7FFFu + ((x.u >> 16) & 1u)) >> 16;
  return (ushort)r;
}
__device__ __forceinline__ float b2f(ushort b) {
  union { uint u; float f; } x; x.u = ((uint)b) << 16;
  return x.f;
}

__device__ __forceinline__ void gl_lds16(const void* g, void* l) {
  __builtin_amdgcn_global_load_lds(
      (const __attribute__((address_space(1))) void*)g,
      (__attribute__((address_space(3))) void*)l, 16, 0, 0);
}

// ---------------- LayerNorm: one wave per row ----------------
__global__ __launch_bounds__(256) void ln_kernel(const float* __restrict__ q,
    const float* __restrict__ w, const float* __restrict__ b,
    ushort* __restrict__ x) {
  int wid = threadIdx.x >> 6, lane = threadIdx.x & 63;
  int row = blockIdx.x * 4 + wid;
  const float* qr = q + (size_t)row * D_;
  float4 v = *(const float4*)(qr + lane * 4);
  float s  = v.x + v.y + v.z + v.w;
  float ss = v.x*v.x + v.y*v.y + v.z*v.z + v.w*v.w;
  #pragma unroll
  for (int off = 32; off; off >>= 1) {
    s  += __shfl_xor(s, off);
    ss += __shfl_xor(ss, off);
  }
  float mu   = s * (1.0f / 256.0f);
  float var  = ss * (1.0f / 256.0f) - mu * mu;
  float rstd = rsqrtf(var + 1e-5f);
  ushort4 o;
  float vv[4] = {v.x, v.y, v.z, v.w};
  ushort ot[4];
  #pragma unroll
  for (int j = 0; j < 4; ++j) {
    int c = lane * 4 + j;
    ot[j] = f2b((vv[j] - mu) * rstd * w[c] + b[c]);
  }
  o.x = ot[0]; o.y = ot[1]; o.z = ot[2]; o.w = ot[3];
  *(ushort4*)(x + (size_t)row * D_ + lane * 4) = o;
}

// ---------------- weight transpose + cast ----------------
__global__ void wt_kernel(const float* __restrict__ in, ushort* __restrict__ out,
                          int R, int C) {
  int o = blockIdx.x * 256 + threadIdx.x;
  if (o >= R * C) return;
  int c = o / R, r = o - c * R;
  out[o] = f2b(in[r * C + c]);
}

// ---------------- GEMM: A[M][K] bf16, Bt[N][K] bf16, tile 128x64, BK=64 ----------------
template<int EPI>
__global__ __launch_bounds__(256) void gemm_kernel(
    const ushort* __restrict__ A, const ushort* __restrict__ Bt,
    const float* __restrict__ bias, void* __restrict__ out,
    int M, int N, int K) {
  __shared__ alignas(16) ushort As[128 * 64];
  __shared__ alignas(16) ushort Bs[64 * 64];
  int tid = threadIdx.x;
  int lane = tid & 63, wid = tid >> 6;
  int m0 = blockIdx.x * 128, n0 = blockIdx.y * 64;
  int r16 = lane & 15, kq = lane >> 4;
  f32x4 acc[2][4] = {};
  for (int k0 = 0; k0 < K; k0 += 64) {
    __syncthreads();
    #pragma unroll
    for (int t = 0; t < 4; ++t) {
      int cid = tid + t * 256;
      int row = cid >> 3, c = cid & 7;
      uint4 d = *(const uint4*)(A + ((size_t)(m0 + row) * K + k0 + c * 8));
      *(uint4*)&As[row * 64 + ((c ^ (row & 7)) * 8)] = d;
    }
    #pragma unroll
    for (int t = 0; t < 2; ++t) {
      int cid = tid + t * 256;
      int row = cid >> 3, c = cid & 7;
      uint4 d = *(const uint4*)(Bt + ((size_t)(n0 + row) * K + k0 + c * 8));
      *(uint4*)&Bs[row * 64 + ((c ^ (row & 7)) * 8)] = d;
    }
    __syncthreads();
    #pragma unroll
    for (int ks = 0; ks < 2; ++ks) {
      bf16_8 af[2], bfr[4];
      int c = ks * 4 + kq;
      #pragma unroll
      for (int fm = 0; fm < 2; ++fm) {
        int r = wid * 32 + fm * 16 + r16;
        af[fm] = *(const bf16_8*)&As[r * 64 + ((c ^ (r & 7)) * 8)];
      }
      #pragma unroll
      for (int fn = 0; fn < 4; ++fn) {
        int r = fn * 16 + r16;
        bfr[fn] = *(const bf16_8*)&Bs[r * 64 + ((c ^ (r & 7)) * 8)];
      }
      #pragma unroll
      for (int fm = 0; fm < 2; ++fm)
        #pragma unroll
        for (int fn = 0; fn < 4; ++fn)
          acc[fm][fn] = __builtin_amdgcn_mfma_f32_16x16x32_bf16(af[fm], bfr[fn], acc[fm][fn], 0, 0, 0);
    }
  }
  #pragma unroll
  for (int fm = 0; fm < 2; ++fm)
    #pragma unroll
    for (int fn = 0; fn < 4; ++fn)
      #pragma unroll
      for (int reg = 0; reg < 4; ++reg) {
        int ml = wid * 32 + fm * 16 + kq * 4 + reg;
        int nl = fn * 16 + r16;
        size_t gm = m0 + ml, gn = n0 + nl;
        float val = acc[fm][fn][reg] + bias[gn];
        if (EPI == 0) {
          float y = val / (1.0f + expf(-val));
          ((ushort*)out)[gm * N + gn] = f2b(y);
        } else if (EPI == 2) {
          float y = val / (1.0f + expf(-val));
          ((ushort*)out)[gn * (size_t)M_TOT + gm] = f2b(y);
        } else {
          ((float*)out)[gm * N + gn] = val;
        }
      }
}

// ---------------- RoPE (outputs pre-scaled by 1/64 so q.k carries 1/MPE) ----------------
__global__ __launch_bounds__(256) void rope_kernel(const ushort* __restrict__ base,
    const float* __restrict__ qw, const float* __restrict__ qb,
    const float* __restrict__ kw, const float* __restrict__ kb,
    ushort* __restrict__ Q, ushort* __restrict__ Kk) {
  int g = blockIdx.x * 256 + threadIdx.x;
  int row = g >> 6, i = g & 63;
  int n = row & (N_ - 1);
  float invf = powf(10000.0f, -(float)i * (1.0f / 64.0f));
  float sv, cv;
  sincosf((float)n * invf, &sv, &cv);
  const float sc = 0.015625f;   // 1/64; (1/64)^2 = 1/4096 = 1/MPE
  float b1 = b2f(base[row * S_ + i]), b2 = b2f(base[row * S_ + 64 + i]);
  float x1q = b1 * qw[i] + qb[i], x2q = b2 * qw[64 + i] + qb[64 + i];
  Q[row * S_ + i]      = f2b((x1q * cv - x2q * sv) * sc);
  Q[row * S_ + 64 + i] = f2b((x2q * cv + x1q * sv) * sc);
  float x1k = b1 * kw[i] + kb[i], x2k = b2 * kw[64 + i] + kb[64 + i];
  Kk[row * S_ + i]      = f2b((x1k * cv - x2k * sv) * sc);
  Kk[row * S_ + 64 + i] = f2b((x2k * cv + x1k * sv) * sc);
}

// ---------------- fused attention (software-pipelined, 1 barrier/iter) ----------------
// grid (32 m-tiles of 128, 4 e-chunks of 128, 2 b), 512 thr (8 waves), 1 block/CU.
// Iter t: stage K_{t+1}, V_t; QK(t) -> sacc; PV(t-1) from Pb/V of prev tile;
// transform sacc+bias -> Pb[t&1]. The P cross-wave exchange rides the single
// end-of-iter barrier. Bias read per-lane from global (L1), off the LDS pipe.
__global__ __launch_bounds__(512, 2) void attn_kernel(
    const ushort* __restrict__ Q, const ushort* __restrict__ Kd,
    const ushort* __restrict__ VT, const ushort* __restrict__ U,
    const float* __restrict__ w_rel, ushort* __restrict__ KVU) {
  __shared__ alignas(16) ushort Ks[2][64 * 128];   // 32 KB
  __shared__ alignas(16) ushort Vs[2][128 * 64];   // 32 KB
  __shared__ alignas(16) ushort Pb[2][128 * 64];   // 32 KB
  const int tid = threadIdx.x, lane = tid & 63, wid = tid >> 6;
  const int b = blockIdx.z, m0 = blockIdx.x * 128, e0 = blockIdx.y * 128;
  const int r16 = lane & 15, kq = lane >> 4;
  const int wqm = wid >> 2, wqn = wid & 3;   // QK: 2m x 4n
  const int wpm = wid >> 1, wpe = wid & 1;   // PV: 4m x 2e

  // Q fragments: wave's 64 m-rows x 128 k (B-operand: col=m)
  bf16_8 qf[4][4];
  #pragma unroll
  for (int fm = 0; fm < 4; ++fm)
    #pragma unroll
    for (int ks = 0; ks < 4; ++ks)
      qf[fm][ks] = *(const bf16_8*)(Q +
          ((size_t)(b * N_ + m0 + wqm * 64 + fm * 16 + r16) * S_ + ks * 32 + kq * 8));

  auto stage_k = [&](int bi, int nt) {
    int n0s = nt * 64;
    #pragma unroll
    for (int tt = 0; tt < 2; ++tt) {           // K tile: 64n x 128s = 1024 chunks
      int p = tt * 512 + tid;
      int row = p >> 4, sc2 = p & 15;
      int cc = sc2 ^ (row & 7);
      gl_lds16(Kd + ((size_t)(b * N_ + n0s + row) * S_ + cc * 8),
               &Ks[bi][(tt * 512 + wid * 64) * 8]);
    }
  };
  auto stage_v = [&](int bi, int nt) {
    int n0s = nt * 64;
    #pragma unroll
    for (int tt = 0; tt < 2; ++tt) {           // V^T tile: 128e x 64n = 1024 chunks
      int p = tt * 512 + tid;
      int er = p >> 3, sc2 = p & 7;
      int nc = sc2 ^ (er & 7);
      gl_lds16(VT + ((size_t)(e0 + er) * M_TOT + b * N_ + n0s + nc * 8),
               &Vs[bi][(tt * 512 + wid * 64) * 8]);
    }
  };

  f32x4 pv[2][4] = {};

  auto do_pv = [&](const ushort* pr, const ushort* vsb) {
    __builtin_amdgcn_s_setprio(1);
    #pragma unroll
    for (int ks = 0; ks < 2; ++ks) {
      bf16_8 pa[2];
      #pragma unroll
      for (int fm = 0; fm < 2; ++fm) {
        int r = wpm * 32 + fm * 16 + r16;
        pa[fm] = *(const bf16_8*)((const char*)pr + ((r * 128 + ks * 64 + kq * 16) ^ ((r & 7) << 4)));
      }
      #pragma unroll
      for (int fe = 0; fe < 4; ++fe) {
        int rv = wpe * 64 + fe * 16 + r16;
        int cv = ks * 4 + kq;
        bf16_8 vf = *(const bf16_8*)&vsb[rv * 64 + ((cv ^ (rv & 7)) * 8)];
        #pragma unroll
        for (int fm = 0; fm < 2; ++fm)
          pv[fm][fe] = __builtin_amdgcn_mfma_f32_16x16x32_bf16(pa[fm], vf, pv[fm][fe], 0, 0, 0);
      }
    }
    __builtin_amdgcn_s_setprio(0);
  };

  stage_k(0, 0);
  asm volatile("s_waitcnt vmcnt(0) lgkmcnt(0)" ::: "memory");
  __builtin_amdgcn_s_barrier();

  auto body = [&](int CUR, int t) {
    // ---- per-lane bias from global (L1-resident; idx always in [0,8190]) ----
    float bw[4][4];
    const float* wb = w_rel + (4095 + 64 * t + 16 * wqn + 4 * kq - m0 - 64 * wqm - r16);
    #pragma unroll
    for (int fm = 0; fm < 4; ++fm)
      #pragma unroll
      for (int rg = 0; rg < 4; ++rg)
        bw[fm][rg] = wb[rg - 16 * fm];
    // ---- stage next K, this V ----
    if (t < 63) stage_k(CUR ^ 1, t + 1);
    stage_v(CUR, t);
    // ---- QK (swapped): sacc[fm] = K_frag x Q_frag -> col=m, rows=n ----
    const ushort* ksb = Ks[CUR];
    f32x4 sacc[4] = {};
    __builtin_amdgcn_s_setprio(1);
    #pragma unroll
    for (int ks = 0; ks < 4; ++ks) {
      int r = wqn * 16 + r16;
      int c = ks * 4 + kq;
      bf16_8 kf = *(const bf16_8*)&ksb[r * 128 + ((c ^ (r & 7)) * 8)];
      #pragma unroll
      for (int fm = 0; fm < 4; ++fm)
        sacc[fm] = __builtin_amdgcn_mfma_f32_16x16x32_bf16(kf, qf[fm][ks], sacc[fm], 0, 0, 0);
    }
    __builtin_amdgcn_s_setprio(0);
    // ---- PV over previous tile (independent of this iter's transform) ----
    if (t > 0) do_pv((const ushort*)&Pb[CUR ^ 1][0], &Vs[CUR ^ 1][0]);
    // ---- transform -> Pb[CUR] (packed uint2 writes) ----
    char* psb = (char*)&Pb[CUR][0];
    #pragma unroll
    for (int fm = 0; fm < 4; ++fm) {
      float t0 = fmaxf(sacc[fm][0] + bw[fm][0], 0.f);
      float t1 = fmaxf(sacc[fm][1] + bw[fm][1], 0.f);
      float t2 = fmaxf(sacc[fm][2] + bw[fm][2], 0.f);
      float t3 = fmaxf(sacc[fm][3] + bw[fm][3], 0.f);
      t0 *= t0; t1 *= t1; t2 *= t2; t3 *= t3;
      uint p01, p23;
      asm("v_cvt_pk_bf16_f32 %0, %1, %2" : "=v"(p01) : "v"(t0), "v"(t1));
      asm("v_cvt_pk_bf16_f32 %0, %1, %2" : "=v"(p23) : "v"(t2), "v"(t3));
      int mp = wqm * 64 + fm * 16 + r16;
      int nb2 = wqn * 32 + kq * 8;
      uint2 pk; pk.x = p01; pk.y = p23;
      *(uint2*)(psb + ((mp * 128 + nb2) ^ ((mp & 7) << 4))) = pk;
    }
    asm volatile("s_waitcnt vmcnt(0) lgkmcnt(0)" ::: "memory");
    __builtin_amdgcn_s_barrier();
  };

  for (int t2 = 0; t2 < 32; ++t2) {
    body(0, 2 * t2);
    body(1, 2 * t2 + 1);
  }
  // drain: PV for tile 63
  do_pv((const ushort*)&Pb[1][0], &Vs[1][0]);

  // ---- epilogue: KVU = bf16(u * pv) ----
  #pragma unroll
  for (int fm = 0; fm < 2; ++fm)
    #pragma unroll
    for (int fe = 0; fe < 4; ++fe)
      #pragma unroll
      for (int reg = 0; reg < 4; ++reg) {
        int ml = wpm * 32 + fm * 16 + kq * 4 + reg;
        size_t grow = (size_t)b * N_ + m0 + ml;
        size_t ge = e0 + wpe * 64 + fe * 16 + r16;
        float uu = b2f(U[grow * E_ + ge]);
        KVU[grow * E_ + ge] = f2b(uu * pv[fm][fe][reg]);
      }
}

extern "C" void kernel_launch(void* const* d_in, const int* in_sizes, int n_in,
                              void* d_out, int out_size, void* d_ws, size_t ws_size,
                              hipStream_t stream) {
  const float* query = (const float*)d_in[0];
  const float* ln_w  = (const float*)d_in[1];
  const float* ln_b  = (const float*)d_in[2];
  const float* Wu    = (const float*)d_in[3];
  const float* bu    = (const float*)d_in[4];
  const float* Wv    = (const float*)d_in[5];
  const float* bv    = (const float*)d_in[6];
  const float* Wbase = (const float*)d_in[7];
  const float* bbase = (const float*)d_in[8];
  const float* q_w   = (const float*)d_in[9];
  const float* q_b   = (const float*)d_in[10];
  const float* k_w   = (const float*)d_in[11];
  const float* k_b   = (const float*)d_in[12];
  const float* w_rel = (const float*)d_in[13];
  const float* Wo    = (const float*)d_in[14];
  const float* bo    = (const float*)d_in[15];
  float* out = (float*)d_out;

  char* ws = (char*)d_ws;
  ushort* X    = (ushort*)(ws);                     // 8192*256  (4 MB)
  ushort* U    = (ushort*)(ws + (4u  << 20));       // 8192*512  (8 MB)
  ushort* VT   = (ushort*)(ws + (12u << 20));       // 512*8192  (8 MB)
  ushort* BASE = (ushort*)(ws + (20u << 20));       // 8192*128  (2 MB)
  ushort* Qb   = (ushort*)(ws + (22u << 20));       // 2 MB
  ushort* Kb   = (ushort*)(ws + (24u << 20));       // 2 MB
  ushort* KVU  = (ushort*)(ws + (26u << 20));       // 8 MB
  ushort* WUT  = (ushort*)(ws + (34u << 20));
  ushort* WVT  = (ushort*)(ws + (34u << 20) + 512*256*2);
  ushort* WBT  = (ushort*)(ws + (34u << 20) + 2*512*256*2);
  ushort* WOT  = (ushort*)(ws + (34u << 20) + 2*512*256*2 + 128*256*2);

  ln_kernel<<<2048, 256, 0, stream>>>(query, ln_w, ln_b, X);
  wt_kernel<<<(512*256 + 255) / 256, 256, 0, stream>>>(Wu, WUT, 256, 512);
  wt_kernel<<<(512*256 + 255) / 256, 256, 0, stream>>>(Wv, WVT, 256, 512);
  wt_kernel<<<(128*256 + 255) / 256, 256, 0, stream>>>(Wbase, WBT, 256, 128);
  wt_kernel<<<(512*256 + 255) / 256, 256, 0, stream>>>(Wo, WOT, 512, 256);
  gemm_kernel<0><<<dim3(64, 8), 256, 0, stream>>>(X, WUT, bu, U, 8192, 512, 256);
  gemm_kernel<2><<<dim3(64, 8), 256, 0, stream>>>(X, WVT, bv, VT, 8192, 512, 256);
  gemm_kernel<0><<<dim3(64, 2), 256, 0, stream>>>(X, WBT, bbase, BASE, 8192, 128, 256);
  rope_kernel<<<2048, 256, 0, stream>>>(BASE, q_w, q_b, k_w, k_b, Qb, Kb);
  attn_kernel<<<dim3(32, 4, 2), 512, 0, stream>>>(Qb, Kb, VT, U, w_rel, KVU);
  gemm_kernel<1><<<dim3(64, 4), 256, 0, stream>>>(KVU, WOT, bo, out, 8192, 256, 512);
}

// Round 7
// 142.389 us; speedup vs baseline: 1.1206x; 1.0257x over previous
//
#include <hip/hip_runtime.h>
#include <hip/hip_bf16.h>
#include <math.h>

typedef __bf16 bf16_8 __attribute__((ext_vector_type(8)));
typedef float f32x4 __attribute__((ext_vector_type(4)));

#define D_ 256
#define S_ 128
#define E_ 512
#define MPE_ 4096
#define B_ 2
#define N_ 4096
#define M_TOT (B_*N_)   // 8192

__device__ __forceinline__ ushort f2b(float f) {
  union { float f; uint u; } x; x.f = f;
  uint r = (x.u + 0x7FFFu + ((x.u >> 16) & 1u)) >> 16;
  return (ushort)r;
}
__device__ __forceinline__ float b2f(ushort b) {
  union { uint u; float f; } x; x.u = ((uint)b) << 16;
  return x.f;
}

__device__ __forceinline__ void gl_lds16(const void* g, void* l) {
  __builtin_amdgcn_global_load_lds(
      (const __attribute__((address_space(1))) void*)g,
      (__attribute__((address_space(3))) void*)l, 16, 0, 0);
}

// ---------------- LayerNorm: one wave per row ----------------
__global__ __launch_bounds__(256) void ln_kernel(const float* __restrict__ q,
    const float* __restrict__ w, const float* __restrict__ b,
    ushort* __restrict__ x) {
  int wid = threadIdx.x >> 6, lane = threadIdx.x & 63;
  int row = blockIdx.x * 4 + wid;
  const float* qr = q + (size_t)row * D_;
  float4 v = *(const float4*)(qr + lane * 4);
  float s  = v.x + v.y + v.z + v.w;
  float ss = v.x*v.x + v.y*v.y + v.z*v.z + v.w*v.w;
  #pragma unroll
  for (int off = 32; off; off >>= 1) {
    s  += __shfl_xor(s, off);
    ss += __shfl_xor(ss, off);
  }
  float mu   = s * (1.0f / 256.0f);
  float var  = ss * (1.0f / 256.0f) - mu * mu;
  float rstd = rsqrtf(var + 1e-5f);
  ushort4 o;
  float vv[4] = {v.x, v.y, v.z, v.w};
  ushort ot[4];
  #pragma unroll
  for (int j = 0; j < 4; ++j) {
    int c = lane * 4 + j;
    ot[j] = f2b((vv[j] - mu) * rstd * w[c] + b[c]);
  }
  o.x = ot[0]; o.y = ot[1]; o.z = ot[2]; o.w = ot[3];
  *(ushort4*)(x + (size_t)row * D_ + lane * 4) = o;
}

// ---------------- weight transpose + cast ----------------
__global__ void wt_kernel(const float* __restrict__ in, ushort* __restrict__ out,
                          int R, int C) {
  int o = blockIdx.x * 256 + threadIdx.x;
  if (o >= R * C) return;
  int c = o / R, r = o - c * R;
  out[o] = f2b(in[r * C + c]);
}

// ---------------- GEMM: A[M][K] bf16, Bt[N][K] bf16, tile 128x64, BK=64 ----------------
template<int EPI>
__global__ __launch_bounds__(256) void gemm_kernel(
    const ushort* __restrict__ A, const ushort* __restrict__ Bt,
    const float* __restrict__ bias, void* __restrict__ out,
    int M, int N, int K) {
  __shared__ alignas(16) ushort As[128 * 64];
  __shared__ alignas(16) ushort Bs[64 * 64];
  int tid = threadIdx.x;
  int lane = tid & 63, wid = tid >> 6;
  int m0 = blockIdx.x * 128, n0 = blockIdx.y * 64;
  int r16 = lane & 15, kq = lane >> 4;
  f32x4 acc[2][4] = {};
  for (int k0 = 0; k0 < K; k0 += 64) {
    __syncthreads();
    #pragma unroll
    for (int t = 0; t < 4; ++t) {
      int cid = tid + t * 256;
      int row = cid >> 3, c = cid & 7;
      uint4 d = *(const uint4*)(A + ((size_t)(m0 + row) * K + k0 + c * 8));
      *(uint4*)&As[row * 64 + ((c ^ (row & 7)) * 8)] = d;
    }
    #pragma unroll
    for (int t = 0; t < 2; ++t) {
      int cid = tid + t * 256;
      int row = cid >> 3, c = cid & 7;
      uint4 d = *(const uint4*)(Bt + ((size_t)(n0 + row) * K + k0 + c * 8));
      *(uint4*)&Bs[row * 64 + ((c ^ (row & 7)) * 8)] = d;
    }
    __syncthreads();
    #pragma unroll
    for (int ks = 0; ks < 2; ++ks) {
      bf16_8 af[2], bfr[4];
      int c = ks * 4 + kq;
      #pragma unroll
      for (int fm = 0; fm < 2; ++fm) {
        int r = wid * 32 + fm * 16 + r16;
        af[fm] = *(const bf16_8*)&As[r * 64 + ((c ^ (r & 7)) * 8)];
      }
      #pragma unroll
      for (int fn = 0; fn < 4; ++fn) {
        int r = fn * 16 + r16;
        bfr[fn] = *(const bf16_8*)&Bs[r * 64 + ((c ^ (r & 7)) * 8)];
      }
      #pragma unroll
      for (int fm = 0; fm < 2; ++fm)
        #pragma unroll
        for (int fn = 0; fn < 4; ++fn)
          acc[fm][fn] = __builtin_amdgcn_mfma_f32_16x16x32_bf16(af[fm], bfr[fn], acc[fm][fn], 0, 0, 0);
    }
  }
  #pragma unroll
  for (int fm = 0; fm < 2; ++fm)
    #pragma unroll
    for (int fn = 0; fn < 4; ++fn)
      #pragma unroll
      for (int reg = 0; reg < 4; ++reg) {
        int ml = wid * 32 + fm * 16 + kq * 4 + reg;
        int nl = fn * 16 + r16;
        size_t gm = m0 + ml, gn = n0 + nl;
        float val = acc[fm][fn][reg] + bias[gn];
        if (EPI == 0) {
          float y = val / (1.0f + expf(-val));
          ((ushort*)out)[gm * N + gn] = f2b(y);
        } else if (EPI == 2) {
          float y = val / (1.0f + expf(-val));
          ((ushort*)out)[gn * (size_t)M_TOT + gm] = f2b(y);
        } else {
          ((float*)out)[gm * N + gn] = val;
        }
      }
}

// ---------------- RoPE (outputs pre-scaled by 1/64 so q.k carries 1/MPE) ----------------
__global__ __launch_bounds__(256) void rope_kernel(const ushort* __restrict__ base,
    const float* __restrict__ qw, const float* __restrict__ qb,
    const float* __restrict__ kw, const float* __restrict__ kb,
    ushort* __restrict__ Q, ushort* __restrict__ Kk) {
  int g = blockIdx.x * 256 + threadIdx.x;
  int row = g >> 6, i = g & 63;
  int n = row & (N_ - 1);
  float invf = powf(10000.0f, -(float)i * (1.0f / 64.0f));
  float sv, cv;
  sincosf((float)n * invf, &sv, &cv);
  const float sc = 0.015625f;   // 1/64; (1/64)^2 = 1/4096 = 1/MPE
  float b1 = b2f(base[row * S_ + i]), b2 = b2f(base[row * S_ + 64 + i]);
  float x1q = b1 * qw[i] + qb[i], x2q = b2 * qw[64 + i] + qb[64 + i];
  Q[row * S_ + i]      = f2b((x1q * cv - x2q * sv) * sc);
  Q[row * S_ + 64 + i] = f2b((x2q * cv + x1q * sv) * sc);
  float x1k = b1 * kw[i] + kb[i], x2k = b2 * kw[64 + i] + kb[64 + i];
  Kk[row * S_ + i]      = f2b((x1k * cv - x2k * sv) * sc);
  Kk[row * S_ + 64 + i] = f2b((x2k * cv + x1k * sv) * sc);
}

// ---------------- fused attention (counted-vmcnt pipeline, T4) ----------------
// grid (32 m-tiles of 128, 4 e-chunks of 128, 2 b), 512 thr (8 waves), 1 block/CU.
// K and V triple-buffered: body(t) issues K(t+2), V(t+1); ends with vmcnt(4)
// (the 4 just-issued loads stay in flight across the barrier). QK(t) reads
// K(t) (landed one iter ago); PV(t-1) reads V(t-1), P(t-1). Tail peeled so the
// wait immediates stay exact (62: vmcnt(2), 63: vmcnt(0)).
__global__ __launch_bounds__(512, 2) void attn_kernel(
    const ushort* __restrict__ Q, const ushort* __restrict__ Kd,
    const ushort* __restrict__ VT, const ushort* __restrict__ U,
    const float* __restrict__ w_rel, ushort* __restrict__ KVU) {
  __shared__ alignas(16) ushort Ks[3][64 * 128];   // 48 KB
  __shared__ alignas(16) ushort Vs[3][128 * 64];   // 48 KB
  __shared__ alignas(16) ushort Pb[2][128 * 64];   // 32 KB
  const int tid = threadIdx.x, lane = tid & 63, wid = tid >> 6;
  const int b = blockIdx.z, m0 = blockIdx.x * 128, e0 = blockIdx.y * 128;
  const int r16 = lane & 15, kq = lane >> 4;
  const int wqm = wid >> 2, wqn = wid & 3;   // QK: 2m x 4n
  const int wpm = wid >> 1, wpe = wid & 1;   // PV: 4m x 2e

  // Q fragments: wave's 64 m-rows x 128 k (B-operand: col=m)
  bf16_8 qf[4][4];
  #pragma unroll
  for (int fm = 0; fm < 4; ++fm)
    #pragma unroll
    for (int ks = 0; ks < 4; ++ks)
      qf[fm][ks] = *(const bf16_8*)(Q +
          ((size_t)(b * N_ + m0 + wqm * 64 + fm * 16 + r16) * S_ + ks * 32 + kq * 8));

  auto stage_k = [&](int bi, int nt) {
    int n0s = nt * 64;
    #pragma unroll
    for (int tt = 0; tt < 2; ++tt) {           // K tile: 64n x 128s = 1024 chunks
      int p = tt * 512 + tid;
      int row = p >> 4, sc2 = p & 15;
      int cc = sc2 ^ (row & 7);
      gl_lds16(Kd + ((size_t)(b * N_ + n0s + row) * S_ + cc * 8),
               &Ks[bi][(tt * 512 + wid * 64) * 8]);
    }
  };
  auto stage_v = [&](int bi, int nt) {
    int n0s = nt * 64;
    #pragma unroll
    for (int tt = 0; tt < 2; ++tt) {           // V^T tile: 128e x 64n = 1024 chunks
      int p = tt * 512 + tid;
      int er = p >> 3, sc2 = p & 7;
      int nc = sc2 ^ (er & 7);
      gl_lds16(VT + ((size_t)(e0 + er) * M_TOT + b * N_ + n0s + nc * 8),
               &Vs[bi][(tt * 512 + wid * 64) * 8]);
    }
  };

  f32x4 pv[2][4] = {};

  auto do_pv = [&](const ushort* pr, const ushort* vsb) {
    __builtin_amdgcn_s_setprio(1);
    #pragma unroll
    for (int ks = 0; ks < 2; ++ks) {
      bf16_8 pa[2];
      #pragma unroll
      for (int fm = 0; fm < 2; ++fm) {
        int r = wpm * 32 + fm * 16 + r16;
        pa[fm] = *(const bf16_8*)((const char*)pr + ((r * 128 + ks * 64 + kq * 16) ^ ((r & 7) << 4)));
      }
      #pragma unroll
      for (int fe = 0; fe < 4; ++fe) {
        int rv = wpe * 64 + fe * 16 + r16;
        int cv = ks * 4 + kq;
        bf16_8 vf = *(const bf16_8*)&vsb[rv * 64 + ((cv ^ (rv & 7)) * 8)];
        #pragma unroll
        for (int fm = 0; fm < 2; ++fm)
          pv[fm][fe] = __builtin_amdgcn_mfma_f32_16x16x32_bf16(pa[fm], vf, pv[fm][fe], 0, 0, 0);
      }
    }
    __builtin_amdgcn_s_setprio(0);
  };

  // prologue: K(0), K(1), V(0) staged and drained
  stage_k(0, 0);
  stage_k(1, 1);
  stage_v(0, 0);
  asm volatile("s_waitcnt vmcnt(0) lgkmcnt(0)" ::: "memory");
  __builtin_amdgcn_s_barrier();

  // body (no final wait/barrier — caller appends the exact waitcnt)
  auto body = [&](int CUR, int t, bool doK, bool doV) {
    // ---- per-lane bias from global (L1-resident; idx always in [0,8190]) ----
    float bw[4][4];
    const float* wb = w_rel + (4095 + 64 * t + 16 * wqn + 4 * kq - m0 - 64 * wqm - r16);
    #pragma unroll
    for (int fm = 0; fm < 4; ++fm)
      #pragma unroll
      for (int rg = 0; rg < 4; ++rg)
        bw[fm][rg] = wb[rg - 16 * fm];
    __builtin_amdgcn_sched_barrier(0);   // pin: bias loads issue before stages
    // ---- stage K(t+2), V(t+1) ----
    if (doK) stage_k((CUR + 2) % 3, t + 2);
    if (doV) stage_v((CUR + 1) % 3, t + 1);
    // ---- QK (swapped): sacc[fm] = K_frag x Q_frag -> col=m, rows=n ----
    const ushort* ksb = Ks[CUR];
    f32x4 sacc[4] = {};
    __builtin_amdgcn_s_setprio(1);
    #pragma unroll
    for (int ks = 0; ks < 4; ++ks) {
      int r = wqn * 16 + r16;
      int c = ks * 4 + kq;
      bf16_8 kf = *(const bf16_8*)&ksb[r * 128 + ((c ^ (r & 7)) * 8)];
      #pragma unroll
      for (int fm = 0; fm < 4; ++fm)
        sacc[fm] = __builtin_amdgcn_mfma_f32_16x16x32_bf16(kf, qf[fm][ks], sacc[fm], 0, 0, 0);
    }
    __builtin_amdgcn_s_setprio(0);
    // ---- PV over previous tile ----
    if (t > 0) do_pv((const ushort*)&Pb[(t - 1) & 1][0], &Vs[(CUR + 2) % 3][0]);
    // ---- transform -> Pb[t&1] (packed uint2 writes) ----
    char* psb = (char*)&Pb[t & 1][0];
    #pragma unroll
    for (int fm = 0; fm < 4; ++fm) {
      float t0 = fmaxf(sacc[fm][0] + bw[fm][0], 0.f);
      float t1 = fmaxf(sacc[fm][1] + bw[fm][1], 0.f);
      float t2 = fmaxf(sacc[fm][2] + bw[fm][2], 0.f);
      float t3 = fmaxf(sacc[fm][3] + bw[fm][3], 0.f);
      t0 *= t0; t1 *= t1; t2 *= t2; t3 *= t3;
      uint p01, p23;
      asm("v_cvt_pk_bf16_f32 %0, %1, %2" : "=v"(p01) : "v"(t0), "v"(t1));
      asm("v_cvt_pk_bf16_f32 %0, %1, %2" : "=v"(p23) : "v"(t2), "v"(t3));
      int mp = wqm * 64 + fm * 16 + r16;
      int nb2 = wqn * 32 + kq * 8;
      uint2 pk; pk.x = p01; pk.y = p23;
      *(uint2*)(psb + ((mp * 128 + nb2) ^ ((mp & 7) << 4))) = pk;
    }
  };

  // main loop: t = 0..59 (all full iterations, wait vmcnt(4))
  for (int tb = 0; tb < 60; tb += 3) {
    body(0, tb,     true, true);
    asm volatile("s_waitcnt vmcnt(4) lgkmcnt(0)" ::: "memory");
    __builtin_amdgcn_s_barrier();
    body(1, tb + 1, true, true);
    asm volatile("s_waitcnt vmcnt(4) lgkmcnt(0)" ::: "memory");
    __builtin_amdgcn_s_barrier();
    body(2, tb + 2, true, true);
    asm volatile("s_waitcnt vmcnt(4) lgkmcnt(0)" ::: "memory");
    __builtin_amdgcn_s_barrier();
  }
  // peeled tail: 60, 61 full; 62 no-K (vmcnt 2); 63 none (vmcnt 0)
  body(0, 60, true, true);
  asm volatile("s_waitcnt vmcnt(4) lgkmcnt(0)" ::: "memory");
  __builtin_amdgcn_s_barrier();
  body(1, 61, true, true);
  asm volatile("s_waitcnt vmcnt(4) lgkmcnt(0)" ::: "memory");
  __builtin_amdgcn_s_barrier();
  body(2, 62, false, true);
  asm volatile("s_waitcnt vmcnt(2) lgkmcnt(0)" ::: "memory");
  __builtin_amdgcn_s_barrier();
  body(0, 63, false, false);
  asm volatile("s_waitcnt vmcnt(0) lgkmcnt(0)" ::: "memory");
  __builtin_amdgcn_s_barrier();
  // drain: PV for tile 63 (V(63) lives in buffer (63+... staged into buf (2+1)%3=0)
  do_pv((const ushort*)&Pb[1][0], &Vs[0][0]);

  // ---- epilogue: KVU = bf16(u * pv) ----
  #pragma unroll
  for (int fm = 0; fm < 2; ++fm)
    #pragma unroll
    for (int fe = 0; fe < 4; ++fe)
      #pragma unroll
      for (int reg = 0; reg < 4; ++reg) {
        int ml = wpm * 32 + fm * 16 + kq * 4 + reg;
        size_t grow = (size_t)b * N_ + m0 + ml;
        size_t ge = e0 + wpe * 64 + fe * 16 + r16;
        float uu = b2f(U[grow * E_ + ge]);
        KVU[grow * E_ + ge] = f2b(uu * pv[fm][fe][reg]);
      }
}

extern "C" void kernel_launch(void* const* d_in, const int* in_sizes, int n_in,
                              void* d_out, int out_size, void* d_ws, size_t ws_size,
                              hipStream_t stream) {
  const float* query = (const float*)d_in[0];
  const float* ln_w  = (const float*)d_in[1];
  const float* ln_b  = (const float*)d_in[2];
  const float* Wu    = (const float*)d_in[3];
  const float* bu    = (const float*)d_in[4];
  const float* Wv    = (const float*)d_in[5];
  const float* bv    = (const float*)d_in[6];
  const float* Wbase = (const float*)d_in[7];
  const float* bbase = (const float*)d_in[8];
  const float* q_w   = (const float*)d_in[9];
  const float* q_b   = (const float*)d_in[10];
  const float* k_w   = (const float*)d_in[11];
  const float* k_b   = (const float*)d_in[12];
  const float* w_rel = (const float*)d_in[13];
  const float* Wo    = (const float*)d_in[14];
  const float* bo    = (const float*)d_in[15];
  float* out = (float*)d_out;

  char* ws = (char*)d_ws;
  ushort* X    = (ushort*)(ws);                     // 8192*256  (4 MB)
  ushort* U    = (ushort*)(ws + (4u  << 20));       // 8192*512  (8 MB)
  ushort* VT   = (ushort*)(ws + (12u << 20));       // 512*8192  (8 MB)
  ushort* BASE = (ushort*)(ws + (20u << 20));       // 8192*128  (2 MB)
  ushort* Qb   = (ushort*)(ws + (22u << 20));       // 2 MB
  ushort* Kb   = (ushort*)(ws + (24u << 20));       // 2 MB
  ushort* KVU  = (ushort*)(ws + (26u << 20));       // 8 MB
  ushort* WUT  = (ushort*)(ws + (34u << 20));
  ushort* WVT  = (ushort*)(ws + (34u << 20) + 512*256*2);
  ushort* WBT  = (ushort*)(ws + (34u << 20) + 2*512*256*2);
  ushort* WOT  = (ushort*)(ws + (34u << 20) + 2*512*256*2 + 128*256*2);

  ln_kernel<<<2048, 256, 0, stream>>>(query, ln_w, ln_b, X);
  wt_kernel<<<(512*256 + 255) / 256, 256, 0, stream>>>(Wu, WUT, 256, 512);
  wt_kernel<<<(512*256 + 255) / 256, 256, 0, stream>>>(Wv, WVT, 256, 512);
  wt_kernel<<<(128*256 + 255) / 256, 256, 0, stream>>>(Wbase, WBT, 256, 128);
  wt_kernel<<<(512*256 + 255) / 256, 256, 0, stream>>>(Wo, WOT, 512, 256);
  gemm_kernel<0><<<dim3(64, 8), 256, 0, stream>>>(X, WUT, bu, U, 8192, 512, 256);
  gemm_kernel<2><<<dim3(64, 8), 256, 0, stream>>>(X, WVT, bv, VT, 8192, 512, 256);
  gemm_kernel<0><<<dim3(64, 2), 256, 0, stream>>>(X, WBT, bbase, BASE, 8192, 128, 256);
  rope_kernel<<<2048, 256, 0, stream>>>(BASE, q_w, q_b, k_w, k_b, Qb, Kb);
  attn_kernel<<<dim3(32, 4, 2), 512, 0, stream>>>(Qb, Kb, VT, U, w_rel, KVU);
  gemm_kernel<1><<<dim3(64, 4), 256, 0, stream>>>(KVU, WOT, bo, out, 8192, 256, 512);
}